// Round 4
// baseline (117.875 us; speedup 1.0000x reference)
//
#include <hip/hip_runtime.h>
#include <hip/hip_bf16.h>
#include <math.h>
#include <cstdint>

#define NUSER 16384   // B*U
#define BB    64
#define UU    256
#define SSLOT 64
#define HD    256
#define DEGS  8
#define DEGU  16
#define SELP  264     // padded LDS row stride (shorts) for sel/w3

typedef __attribute__((ext_vector_type(8))) short short8;
typedef __attribute__((ext_vector_type(4))) float f32x4;

static __device__ __forceinline__ __hip_bfloat16 f2b(float x) { return __float2bfloat16(x); }
static __device__ __forceinline__ float uf(unsigned u) { return __uint_as_float(u); }
static __device__ __forceinline__ unsigned pack2(float x, float y) {
  union { __hip_bfloat16 h[2]; unsigned u; } cv;
  cv.h[0] = f2b(x); cv.h[1] = f2b(y);
  return cv.u;
}

// ---------------------------------------------------------------------------
// K0: connection bitmasks + weight transposes to bf16 (W2T[n][k], W3T[n][k]).
// ---------------------------------------------------------------------------
__global__ __launch_bounds__(256) void k_setup(
    const int* __restrict__ dst_u2s, const int* __restrict__ dst_u2u,
    const float* __restrict__ oW2, const float* __restrict__ sW2,
    const float* __restrict__ sW3,
    unsigned long long* __restrict__ connS, unsigned long long* __restrict__ connU,
    __hip_bfloat16* __restrict__ W2T_o, __hip_bfloat16* __restrict__ W2T_s,
    __hip_bfloat16* __restrict__ W3T_s) {
  const int b = blockIdx.x, t = threadIdx.x;
  W2T_o[b * HD + t] = f2b(oW2[t * HD + b]);
  W2T_s[b * HD + t] = f2b(sW2[t * HD + b]);
  if (b < SSLOT) W3T_s[b * HD + t] = f2b(sW3[t * SSLOT + b]);
  if (b < NUSER / 256) {
    const int u = b * 256 + t;
    unsigned long long ms = 0ull;
    #pragma unroll
    for (int i = 0; i < DEGS; ++i) ms |= 1ull << (dst_u2s[u * DEGS + i] & 63);
    connS[u] = ms;
    unsigned long long m0 = 0, m1 = 0, m2 = 0, m3 = 0;
    #pragma unroll
    for (int i = 0; i < DEGU; ++i) {
      int slot = dst_u2u[u * DEGU + i] & 255;
      unsigned long long bit = 1ull << (slot & 63);
      int w = slot >> 6;
      if (w == 0) m0 |= bit; else if (w == 1) m1 |= bit; else if (w == 2) m2 |= bit; else m3 |= bit;
    }
    connU[u * 4 + 0] = m0; connU[u * 4 + 1] = m1;
    connU[u * 4 + 2] = m2; connU[u * 4 + 3] = m3;
  }
}

// ---------------------------------------------------------------------------
// K1: per-slot partial layer-1 products, stored bf16.
// ---------------------------------------------------------------------------
__global__ __launch_bounds__(256) void k_pq(
    const float* __restrict__ xu, const float* __restrict__ xs,
    const float* __restrict__ oW1, const float* __restrict__ sW1,
    __hip_bfloat16* __restrict__ P_o, __hip_bfloat16* __restrict__ P_s,
    __hip_bfloat16* __restrict__ Q_o, __hip_bfloat16* __restrict__ Q_s) {
  const int t = threadIdx.x;
  const int wg = blockIdx.x;            // 0..63 server slots, 64..319 user slots
  __shared__ float lx[BB * 16];
  if (wg < SSLOT) {
    const int s = wg;
    for (int i = t; i < BB * 16; i += 256) {
      int b = i >> 4, d = i & 15;
      lx[i] = xs[(b * SSLOT + s) * 16 + d];
    }
    __syncthreads();
    float wo[16], wsv[16];
    #pragma unroll
    for (int d = 0; d < 16; ++d) {
      int row = s * 16 + d;
      wo[d] = oW1[row * HD + t];
      wsv[d] = sW1[row * HD + t];
    }
    for (int b = 0; b < BB; ++b) {
      float ao = 0.f, as = 0.f;
      #pragma unroll
      for (int d = 0; d < 16; ++d) {
        float f = lx[b * 16 + d];
        ao = fmaf(f, wo[d], ao);
        as = fmaf(f, wsv[d], as);
      }
      P_o[(b * SSLOT + s) * HD + t] = f2b(ao);
      P_s[(b * SSLOT + s) * HD + t] = f2b(as);
    }
  } else {
    const int v = wg - SSLOT;
    for (int i = t; i < BB * 16; i += 256) {
      int b = i >> 4, d = i & 15;
      lx[i] = xu[(b * UU + v) * 16 + d];
    }
    __syncthreads();
    float wo[16], wsv[16];
    #pragma unroll
    for (int d = 0; d < 16; ++d) {
      int row = SSLOT * 16 + v * 16 + d;
      wo[d] = oW1[row * HD + t];
      wsv[d] = sW1[row * HD + t];
    }
    for (int b = 0; b < BB; ++b) {
      float ao = 0.f, as = 0.f;
      #pragma unroll
      for (int d = 0; d < 16; ++d) {
        float f = lx[b * 16 + d];
        ao = fmaf(f, wo[d], ao);
        as = fmaf(f, wsv[d], as);
      }
      Q_o[(b * UU + v) * HD + t] = f2b(ao);
      Q_s[(b * UU + v) * HD + t] = f2b(as);
    }
  }
}

// ---------------------------------------------------------------------------
// K2: fused per-MLP pipeline. grid (512 M-tiles, 2 MLPs), 256 thr, ~50 KB LDS.
// Phase 0: gather h1 tile (32 users x 256) from P/Q via masks -> swizzled LDS A.
// Phase 1: kt-loop MFMA vs W2T staged in LDS  (h2 = sigmoid(...) in regs).
// Phase 2 (mlp=0): oW3 head + softmax2 -> out.
// Phase 2 (mlp=1): sel LDS tile, MFMA vs W3T, masked softmax -> out.
// ---------------------------------------------------------------------------
__global__ __launch_bounds__(256) void k_mlp(
    const unsigned long long* __restrict__ connS,
    const unsigned long long* __restrict__ connU,
    const __hip_bfloat16* __restrict__ P_o, const __hip_bfloat16* __restrict__ P_s,
    const __hip_bfloat16* __restrict__ Q_o, const __hip_bfloat16* __restrict__ Q_s,
    const float* __restrict__ ob1, const float* __restrict__ sb1,
    const __hip_bfloat16* __restrict__ W2T_o, const __hip_bfloat16* __restrict__ W2T_s,
    const float* __restrict__ ob2, const float* __restrict__ sb2,
    const float* __restrict__ oW3, const float* __restrict__ ob3,
    const __hip_bfloat16* __restrict__ W3T_s, const float* __restrict__ sb3,
    float* __restrict__ out) {
  const int mlp = blockIdx.y;
  const int x = blockIdx.x;
  const int blk = (x & 7) * 64 + (x >> 3);      // XCD-affine, bijective (512%8==0)
  const int u0 = blk * 32;
  const int t = threadIdx.x, lane = t & 63, wid = t >> 6;
  const int lo = lane & 15, hi = lane >> 4;

  const __hip_bfloat16* P   = mlp ? P_s : P_o;
  const __hip_bfloat16* Q   = mlp ? Q_s : Q_o;
  const __hip_bfloat16* W2T = mlp ? W2T_s : W2T_o;
  const float* b1 = mlp ? sb1 : ob1;
  const float* b2 = mlp ? sb2 : ob2;

  __shared__ __align__(16) char lds[51200];
  short* As  = (short*)lds;              // 32 x 256 (16 KB), chunk-swizzled
  short* Bs  = (short*)(lds + 16384);    // 256 x 64 (32 KB), chunk-swizzled
  float* part = (float*)(lds + 49152);   // [4][32][2] (1 KB)   (mlp==0)
  short* sel = (short*)lds;              // 32 x SELP (mlp==1 phase 2)
  short* w3  = (short*)(lds + 16896);    // 64 x SELP (mlp==1 phase 2)

  // ---- Phase 0: gather h1 rows into As ----
  {
    const int b = u0 >> 8;
    float4 bias = *(const float4*)(b1 + lane * 4);
    const __hip_bfloat16* Pb = P + (size_t)b * SSLOT * HD + lane * 4;
    const __hip_bfloat16* Qb = Q + (size_t)b * UU * HD + lane * 4;
    #pragma unroll
    for (int i = 0; i < 8; ++i) {
      const int row = wid * 8 + i;
      const int u = u0 + row;
      float4 a = bias;
      unsigned long long ms = connS[u];
      while (ms) {
        int s = __ffsll(ms) - 1; ms &= ms - 1;
        uint2 v = *(const uint2*)(Pb + s * HD);
        a.x += uf(v.x << 16); a.y += uf(v.x & 0xFFFF0000u);
        a.z += uf(v.y << 16); a.w += uf(v.y & 0xFFFF0000u);
      }
      #pragma unroll
      for (int w = 0; w < 4; ++w) {
        unsigned long long mu = connU[u * 4 + w];
        while (mu) {
          int v = (w << 6) + __ffsll(mu) - 1; mu &= mu - 1;
          uint2 q = *(const uint2*)(Qb + v * HD);
          a.x += uf(q.x << 16); a.y += uf(q.x & 0xFFFF0000u);
          a.z += uf(q.y << 16); a.w += uf(q.y & 0xFFFF0000u);
        }
      }
      uint2 r;
      r.x = pack2(fmaxf(a.x, 0.f), fmaxf(a.y, 0.f));
      r.y = pack2(fmaxf(a.z, 0.f), fmaxf(a.w, 0.f));
      // col chunk = lane>>1 (0..31), swizzle within row, 8B halves by lane&1
      *(uint2*)&As[row * 256 + ((lane >> 1) ^ (row & 7)) * 8 + (lane & 1) * 4] = r;
    }
  }

  // ---- Phase 1: h2 tile in registers via MFMA ----
  f32x4 acc[2][4] = {};
  for (int kt = 0; kt < 4; ++kt) {
    #pragma unroll
    for (int i = 0; i < 8; ++i) {              // Bs: 2048 16B chunks
      int c = t + i * 256;
      int row = c >> 3, cc = c & 7;
      *(short8*)&Bs[row * 64 + (cc ^ (row & 7)) * 8] =
          *(const short8*)(W2T + (size_t)row * HD + kt * 64 + cc * 8);
    }
    __syncthreads();
    #pragma unroll
    for (int ks = 0; ks < 2; ++ks) {
      const int ca = kt * 8 + ks * 4 + hi;     // A chunk (of 32)
      const int cb8 = ks * 4 + hi;             // B chunk (of 8)
      short8 af[2], bf[4];
      #pragma unroll
      for (int rb = 0; rb < 2; ++rb) {
        int row = rb * 16 + lo;
        af[rb] = *(const short8*)&As[row * 256 + (ca ^ (row & 7)) * 8];
      }
      #pragma unroll
      for (int cb = 0; cb < 4; ++cb) {
        int rn = wid * 64 + cb * 16 + lo;
        bf[cb] = *(const short8*)&Bs[rn * 64 + (cb8 ^ (rn & 7)) * 8];
      }
      #pragma unroll
      for (int rb = 0; rb < 2; ++rb)
        #pragma unroll
        for (int cb = 0; cb < 4; ++cb)
          acc[rb][cb] = __builtin_amdgcn_mfma_f32_16x16x32_bf16(af[rb], bf[cb], acc[rb][cb], 0, 0, 0);
    }
    __syncthreads();
  }

  // ---- Phase 2 ----
  if (mlp == 0) {
    float p0[2][4] = {}, p1[2][4] = {};
    #pragma unroll
    for (int cb = 0; cb < 4; ++cb) {
      int n = wid * 64 + cb * 16 + lo;
      float bs = b2[n], w0 = oW3[2 * n], w1 = oW3[2 * n + 1];
      #pragma unroll
      for (int rb = 0; rb < 2; ++rb)
        #pragma unroll
        for (int j = 0; j < 4; ++j) {
          float sig = 1.0f / (1.0f + __expf(-(acc[rb][cb][j] + bs)));
          p0[rb][j] = fmaf(sig, w0, p0[rb][j]);
          p1[rb][j] = fmaf(sig, w1, p1[rb][j]);
        }
    }
    #pragma unroll
    for (int rb = 0; rb < 2; ++rb)
      #pragma unroll
      for (int j = 0; j < 4; ++j) {
        #pragma unroll
        for (int off = 1; off < 16; off <<= 1) {
          p0[rb][j] += __shfl_xor(p0[rb][j], off, 64);
          p1[rb][j] += __shfl_xor(p1[rb][j], off, 64);
        }
        if (lo == 0) {
          int row = rb * 16 + hi * 4 + j;
          part[wid * 64 + row * 2 + 0] = p0[rb][j];
          part[wid * 64 + row * 2 + 1] = p1[rb][j];
        }
      }
    __syncthreads();
    if (t < 32) {
      float q0 = part[t * 2] + part[64 + t * 2] + part[128 + t * 2] + part[192 + t * 2] + ob3[0];
      float q1 = part[t * 2 + 1] + part[64 + t * 2 + 1] + part[128 + t * 2 + 1] + part[192 + t * 2 + 1] + ob3[1];
      float m2 = fmaxf(q0, q1);
      float e0 = __expf(q0 - m2), e1 = __expf(q1 - m2);
      float iv = 1.0f / (e0 + e1);
      float2 r; r.x = e0 * iv; r.y = e1 * iv;
      *(float2*)(out + (size_t)(u0 + t) * 2) = r;
    }
  } else {
    // 2a: sigmoid -> sel LDS (bf16); stage W3T -> w3 LDS
    #pragma unroll
    for (int cb = 0; cb < 4; ++cb) {
      int n = wid * 64 + cb * 16 + lo;
      float bs = b2[n];
      #pragma unroll
      for (int rb = 0; rb < 2; ++rb)
        #pragma unroll
        for (int j = 0; j < 4; ++j) {
          int row = rb * 16 + hi * 4 + j;
          float sig = 1.0f / (1.0f + __expf(-(acc[rb][cb][j] + bs)));
          sel[row * SELP + n] = (short)pack2(sig, 0.f);
        }
    }
    #pragma unroll
    for (int i = 0; i < 8; ++i) {              // w3: 64 rows x 32 chunks
      int c = t + i * 256;
      int row = c >> 5, cc = c & 31;
      *(short8*)&w3[row * SELP + cc * 8] =
          *(const short8*)(W3T_s + (size_t)row * HD + cc * 8);
    }
    __syncthreads();
    // 2b: lg = sel @ w3^T (waves 0,1: 16 rows each), then masked softmax
    if (wid < 2) {
      f32x4 acc2[4] = {};
      #pragma unroll
      for (int ks = 0; ks < 8; ++ks) {
        int c = ks * 4 + hi;
        short8 af = *(const short8*)&sel[(wid * 16 + lo) * SELP + c * 8];
        #pragma unroll
        for (int cb = 0; cb < 4; ++cb) {
          short8 bf = *(const short8*)&w3[(cb * 16 + lo) * SELP + c * 8];
          acc2[cb] = __builtin_amdgcn_mfma_f32_16x16x32_bf16(af, bf, acc2[cb], 0, 0, 0);
        }
      }
      float sb3n[4];
      #pragma unroll
      for (int cb = 0; cb < 4; ++cb) sb3n[cb] = sb3[cb * 16 + lo];
      const int ubase = u0 + wid * 16 + hi * 4;
      #pragma unroll
      for (int j = 0; j < 4; ++j) {
        unsigned long long m = connS[ubase + j];
        float v[4]; bool ok[4];
        float mx = -INFINITY;
        #pragma unroll
        for (int cb = 0; cb < 4; ++cb) {
          int n = cb * 16 + lo;
          ok[cb] = (m >> n) & 1ull;
          v[cb] = ok[cb] ? (acc2[cb][j] + sb3n[cb]) : -INFINITY;
          mx = fmaxf(mx, v[cb]);
        }
        #pragma unroll
        for (int off = 1; off < 16; off <<= 1) mx = fmaxf(mx, __shfl_xor(mx, off, 64));
        float e[4], ssum = 0.f;
        #pragma unroll
        for (int cb = 0; cb < 4; ++cb) {
          e[cb] = ok[cb] ? __expf(v[cb] - mx) : 0.f;
          ssum += e[cb];
        }
        #pragma unroll
        for (int off = 1; off < 16; off <<= 1) ssum += __shfl_xor(ssum, off, 64);
        float iv = 1.0f / ssum;
        #pragma unroll
        for (int cb = 0; cb < 4; ++cb) {
          int n = cb * 16 + lo;
          out[(size_t)NUSER * 2 + (size_t)(ubase + j) * SSLOT + n] = e[cb] * iv;
        }
      }
    }
  }
}

// ---------------------------------------------------------------------------
extern "C" void kernel_launch(void* const* d_in, const int* in_sizes, int n_in,
                              void* d_out, int out_size, void* d_ws, size_t ws_size,
                              hipStream_t stream) {
  const float* x_user   = (const float*)d_in[0];
  const float* x_server = (const float*)d_in[1];
  const int*   dst_u2s  = (const int*)d_in[3];
  const int*   dst_u2u  = (const int*)d_in[5];
  const float* oW1 = (const float*)d_in[6];
  const float* ob1 = (const float*)d_in[7];
  const float* oW2 = (const float*)d_in[8];
  const float* ob2 = (const float*)d_in[9];
  const float* oW3 = (const float*)d_in[10];
  const float* ob3 = (const float*)d_in[11];
  const float* sW1 = (const float*)d_in[12];
  const float* sb1 = (const float*)d_in[13];
  const float* sW2 = (const float*)d_in[14];
  const float* sb2 = (const float*)d_in[15];
  const float* sW3 = (const float*)d_in[16];
  const float* sb3 = (const float*)d_in[17];

  char* ws = (char*)d_ws;
  unsigned long long* connS = (unsigned long long*)(ws + 0);         // 128 KB
  unsigned long long* connU = (unsigned long long*)(ws + 131072);    // 512 KB
  __hip_bfloat16* P_o  = (__hip_bfloat16*)(ws + 655360);             // 2 MB
  __hip_bfloat16* P_s  = (__hip_bfloat16*)(ws + 2752512);            // 2 MB
  __hip_bfloat16* Q_o  = (__hip_bfloat16*)(ws + 4849664);            // 8 MB
  __hip_bfloat16* Q_s  = (__hip_bfloat16*)(ws + 13238272);           // 8 MB
  __hip_bfloat16* W2T_o = (__hip_bfloat16*)(ws + 21626880);          // 128 KB
  __hip_bfloat16* W2T_s = (__hip_bfloat16*)(ws + 21757952);          // 128 KB
  __hip_bfloat16* W3T_s = (__hip_bfloat16*)(ws + 21889024);          // 32 KB
  float* out = (float*)d_out;

  k_setup<<<256, 256, 0, stream>>>(dst_u2s, dst_u2u, oW2, sW2, sW3,
                                   connS, connU, W2T_o, W2T_s, W3T_s);
  k_pq<<<SSLOT + UU, 256, 0, stream>>>(x_user, x_server, oW1, sW1, P_o, P_s, Q_o, Q_s);
  k_mlp<<<dim3(512, 2), 256, 0, stream>>>(connS, connU, P_o, P_s, Q_o, Q_s,
                                          ob1, sb1, W2T_o, W2T_s, ob2, sb2,
                                          oW3, ob3, W3T_s, sb3, out);
}

// Round 5
// 83.075 us; speedup vs baseline: 1.4189x; 1.4189x over previous
//
#include <hip/hip_runtime.h>
#include <hip/hip_bf16.h>
#include <math.h>
#include <cstdint>

#define NUSER 16384   // B*U
#define BB    64
#define UU    256
#define SSLOT 64
#define HD    256
#define DEGS  8
#define DEGU  16

typedef __attribute__((ext_vector_type(8))) short short8;
typedef __attribute__((ext_vector_type(4))) float f32x4;

static __device__ __forceinline__ __hip_bfloat16 f2b(float x) { return __float2bfloat16(x); }
static __device__ __forceinline__ float uf(unsigned u) { return __uint_as_float(u); }
static __device__ __forceinline__ unsigned pack2(float x, float y) {
  union { __hip_bfloat16 h[2]; unsigned u; } cv;
  cv.h[0] = f2b(x); cv.h[1] = f2b(y);
  return cv.u;
}

// ---------------------------------------------------------------------------
// K0: connection bitmasks + weight transposes to bf16 (W2T[n][k], W3T[n][k]).
// ---------------------------------------------------------------------------
__global__ __launch_bounds__(256) void k_setup(
    const int* __restrict__ dst_u2s, const int* __restrict__ dst_u2u,
    const float* __restrict__ oW2, const float* __restrict__ sW2,
    const float* __restrict__ sW3,
    unsigned long long* __restrict__ connS, unsigned long long* __restrict__ connU,
    __hip_bfloat16* __restrict__ W2T_o, __hip_bfloat16* __restrict__ W2T_s,
    __hip_bfloat16* __restrict__ W3T_s) {
  const int b = blockIdx.x, t = threadIdx.x;
  W2T_o[b * HD + t] = f2b(oW2[t * HD + b]);
  W2T_s[b * HD + t] = f2b(sW2[t * HD + b]);
  if (b < SSLOT) W3T_s[b * HD + t] = f2b(sW3[t * SSLOT + b]);
  if (b < NUSER / 256) {
    const int u = b * 256 + t;
    unsigned long long ms = 0ull;
    #pragma unroll
    for (int i = 0; i < DEGS; ++i) ms |= 1ull << (dst_u2s[u * DEGS + i] & 63);
    connS[u] = ms;
    unsigned long long m0 = 0, m1 = 0, m2 = 0, m3 = 0;
    #pragma unroll
    for (int i = 0; i < DEGU; ++i) {
      int slot = dst_u2u[u * DEGU + i] & 255;
      unsigned long long bit = 1ull << (slot & 63);
      int w = slot >> 6;
      if (w == 0) m0 |= bit; else if (w == 1) m1 |= bit; else if (w == 2) m2 |= bit; else m3 |= bit;
    }
    connU[u * 4 + 0] = m0; connU[u * 4 + 1] = m1;
    connU[u * 4 + 2] = m2; connU[u * 4 + 3] = m3;
  }
}

// ---------------------------------------------------------------------------
// K1: per-slot partial layer-1 products, stored bf16.
// ---------------------------------------------------------------------------
__global__ __launch_bounds__(256) void k_pq(
    const float* __restrict__ xu, const float* __restrict__ xs,
    const float* __restrict__ oW1, const float* __restrict__ sW1,
    __hip_bfloat16* __restrict__ P_o, __hip_bfloat16* __restrict__ P_s,
    __hip_bfloat16* __restrict__ Q_o, __hip_bfloat16* __restrict__ Q_s) {
  const int t = threadIdx.x;
  const int wg = blockIdx.x;            // 0..63 server slots, 64..319 user slots
  __shared__ float lx[BB * 16];
  if (wg < SSLOT) {
    const int s = wg;
    for (int i = t; i < BB * 16; i += 256) {
      int b = i >> 4, d = i & 15;
      lx[i] = xs[(b * SSLOT + s) * 16 + d];
    }
    __syncthreads();
    float wo[16], wsv[16];
    #pragma unroll
    for (int d = 0; d < 16; ++d) {
      int row = s * 16 + d;
      wo[d] = oW1[row * HD + t];
      wsv[d] = sW1[row * HD + t];
    }
    for (int b = 0; b < BB; ++b) {
      float ao = 0.f, as = 0.f;
      #pragma unroll
      for (int d = 0; d < 16; ++d) {
        float f = lx[b * 16 + d];
        ao = fmaf(f, wo[d], ao);
        as = fmaf(f, wsv[d], as);
      }
      P_o[(b * SSLOT + s) * HD + t] = f2b(ao);
      P_s[(b * SSLOT + s) * HD + t] = f2b(as);
    }
  } else {
    const int v = wg - SSLOT;
    for (int i = t; i < BB * 16; i += 256) {
      int b = i >> 4, d = i & 15;
      lx[i] = xu[(b * UU + v) * 16 + d];
    }
    __syncthreads();
    float wo[16], wsv[16];
    #pragma unroll
    for (int d = 0; d < 16; ++d) {
      int row = SSLOT * 16 + v * 16 + d;
      wo[d] = oW1[row * HD + t];
      wsv[d] = sW1[row * HD + t];
    }
    for (int b = 0; b < BB; ++b) {
      float ao = 0.f, as = 0.f;
      #pragma unroll
      for (int d = 0; d < 16; ++d) {
        float f = lx[b * 16 + d];
        ao = fmaf(f, wo[d], ao);
        as = fmaf(f, wsv[d], as);
      }
      Q_o[(b * UU + v) * HD + t] = f2b(ao);
      Q_s[(b * UU + v) * HD + t] = f2b(as);
    }
  }
}

// ---------------------------------------------------------------------------
// K2: h1 = relu(b1 + sum connected P + sum connected Q). One user per wave,
// lane owns 4 cols (uint2 loads). High-occupancy, latency hidden by TLP.
// ---------------------------------------------------------------------------
__global__ __launch_bounds__(256) void k_h1(
    const unsigned long long* __restrict__ connS,
    const unsigned long long* __restrict__ connU,
    const __hip_bfloat16* __restrict__ P_o, const __hip_bfloat16* __restrict__ P_s,
    const __hip_bfloat16* __restrict__ Q_o, const __hip_bfloat16* __restrict__ Q_s,
    const float* __restrict__ ob1, const float* __restrict__ sb1,
    __hip_bfloat16* __restrict__ h1o, __hip_bfloat16* __restrict__ h1s) {
  const int orig = blockIdx.x;                       // 4096 blocks
  const int blk = (orig & 7) * (4096 / 8) + (orig >> 3);  // XCD-affine chunks
  const int wid = threadIdx.x >> 6, lane = threadIdx.x & 63;
  const int u = blk * 4 + wid;
  const int b = u >> 8;
  const int c0 = lane * 4;
  float4 ao = *(const float4*)(ob1 + c0);
  float4 asv = *(const float4*)(sb1 + c0);
  const __hip_bfloat16* Pob = P_o + (size_t)b * SSLOT * HD + c0;
  const __hip_bfloat16* Psb = P_s + (size_t)b * SSLOT * HD + c0;
  unsigned long long ms = connS[u];
  while (ms) {
    int s = __ffsll(ms) - 1; ms &= ms - 1;
    uint2 vo = *(const uint2*)(Pob + s * HD);
    uint2 vs = *(const uint2*)(Psb + s * HD);
    ao.x += uf(vo.x << 16); ao.y += uf(vo.x & 0xFFFF0000u);
    ao.z += uf(vo.y << 16); ao.w += uf(vo.y & 0xFFFF0000u);
    asv.x += uf(vs.x << 16); asv.y += uf(vs.x & 0xFFFF0000u);
    asv.z += uf(vs.y << 16); asv.w += uf(vs.y & 0xFFFF0000u);
  }
  const __hip_bfloat16* Qob = Q_o + (size_t)b * UU * HD + c0;
  const __hip_bfloat16* Qsb = Q_s + (size_t)b * UU * HD + c0;
  #pragma unroll
  for (int w = 0; w < 4; ++w) {
    unsigned long long mu = connU[u * 4 + w];
    while (mu) {
      int v = (w << 6) + __ffsll(mu) - 1;
      mu &= mu - 1;
      uint2 vo = *(const uint2*)(Qob + v * HD);
      uint2 vs = *(const uint2*)(Qsb + v * HD);
      ao.x += uf(vo.x << 16); ao.y += uf(vo.x & 0xFFFF0000u);
      ao.z += uf(vo.y << 16); ao.w += uf(vo.y & 0xFFFF0000u);
      asv.x += uf(vs.x << 16); asv.y += uf(vs.x & 0xFFFF0000u);
      asv.z += uf(vs.y << 16); asv.w += uf(vs.y & 0xFFFF0000u);
    }
  }
  uint2 ro, rs;
  ro.x = pack2(fmaxf(ao.x, 0.f), fmaxf(ao.y, 0.f));
  ro.y = pack2(fmaxf(ao.z, 0.f), fmaxf(ao.w, 0.f));
  rs.x = pack2(fmaxf(asv.x, 0.f), fmaxf(asv.y, 0.f));
  rs.y = pack2(fmaxf(asv.z, 0.f), fmaxf(asv.w, 0.f));
  *(uint2*)(h1o + (size_t)u * HD + c0) = ro;
  *(uint2*)(h1s + (size_t)u * HD + c0) = rs;
}

// ---------------------------------------------------------------------------
// K3: layer-2 GEMM + fused heads. grid (512 M-tiles, 2 MLPs), 256 thr.
// A tile (32 users x 256) in swizzled LDS; B read DIRECTLY from L2-resident
// W2T (no LDS staging, no k-loop barriers). Epilogues:
//   mlp=0: oW3 head + softmax2;  mlp=1: sel GEMM (B=W3T from L2) + masked softmax.
// ---------------------------------------------------------------------------
__global__ __launch_bounds__(256) void k_heads(
    const __hip_bfloat16* __restrict__ h1o, const __hip_bfloat16* __restrict__ h1s,
    const __hip_bfloat16* __restrict__ W2T_o, const __hip_bfloat16* __restrict__ W2T_s,
    const float* __restrict__ ob2, const float* __restrict__ sb2,
    const float* __restrict__ oW3, const float* __restrict__ ob3,
    const __hip_bfloat16* __restrict__ W3T_s, const float* __restrict__ sb3,
    const unsigned long long* __restrict__ connS,
    float* __restrict__ out) {
  const int mlp = blockIdx.y;
  const int x = blockIdx.x;
  const int blk = (x & 7) * 64 + (x >> 3);      // XCD-affine, bijective (512%8==0)
  const int u0 = blk * 32;
  const int t = threadIdx.x, lane = t & 63, wid = t >> 6;
  const int lo = lane & 15, hi = lane >> 4;

  const __hip_bfloat16* A   = mlp ? h1s : h1o;
  const __hip_bfloat16* W2T = mlp ? W2T_s : W2T_o;
  const float* b2 = mlp ? sb2 : ob2;

  __shared__ __align__(16) char lds[16384 + 1024];
  short* As  = (short*)lds;              // 32 x 256 bf16, chunk-swizzled
  float* part = (float*)(lds + 16384);   // [4][32][2] partials (mlp==0)

  // ---- stage A tile (1024 16B chunks) ----
  #pragma unroll
  for (int i = 0; i < 4; ++i) {
    int c = t + i * 256;
    int row = c >> 5, cc = c & 31;
    *(short8*)&As[row * 256 + (cc ^ (row & 7)) * 8] =
        *(const short8*)(A + (size_t)(u0 + row) * HD + cc * 8);
  }
  __syncthreads();

  // ---- K-loop: 8 ksteps, B fragments straight from global (L2) ----
  f32x4 acc[2][4] = {};
  #pragma unroll
  for (int ks = 0; ks < 8; ++ks) {
    short8 af[2], bf[4];
    #pragma unroll
    for (int rb = 0; rb < 2; ++rb) {
      int row = rb * 16 + lo;
      int ca = ks * 4 + hi;
      af[rb] = *(const short8*)&As[row * 256 + (ca ^ (row & 7)) * 8];
    }
    #pragma unroll
    for (int cb = 0; cb < 4; ++cb) {
      int n = wid * 64 + cb * 16 + lo;
      bf[cb] = *(const short8*)(W2T + (size_t)n * HD + ks * 32 + hi * 8);
    }
    #pragma unroll
    for (int rb = 0; rb < 2; ++rb)
      #pragma unroll
      for (int cb = 0; cb < 4; ++cb)
        acc[rb][cb] = __builtin_amdgcn_mfma_f32_16x16x32_bf16(af[rb], bf[cb], acc[rb][cb], 0, 0, 0);
  }

  // ---- epilogues ----
  if (mlp == 0) {
    float p0[2][4] = {}, p1[2][4] = {};
    #pragma unroll
    for (int cb = 0; cb < 4; ++cb) {
      int n = wid * 64 + cb * 16 + lo;
      float bs = b2[n], w0 = oW3[2 * n], w1 = oW3[2 * n + 1];
      #pragma unroll
      for (int rb = 0; rb < 2; ++rb)
        #pragma unroll
        for (int j = 0; j < 4; ++j) {
          float sig = 1.0f / (1.0f + __expf(-(acc[rb][cb][j] + bs)));
          p0[rb][j] = fmaf(sig, w0, p0[rb][j]);
          p1[rb][j] = fmaf(sig, w1, p1[rb][j]);
        }
    }
    #pragma unroll
    for (int rb = 0; rb < 2; ++rb)
      #pragma unroll
      for (int j = 0; j < 4; ++j) {
        #pragma unroll
        for (int off = 1; off < 16; off <<= 1) {
          p0[rb][j] += __shfl_xor(p0[rb][j], off, 64);
          p1[rb][j] += __shfl_xor(p1[rb][j], off, 64);
        }
        if (lo == 0) {
          int row = rb * 16 + hi * 4 + j;
          part[wid * 64 + row * 2 + 0] = p0[rb][j];
          part[wid * 64 + row * 2 + 1] = p1[rb][j];
        }
      }
    __syncthreads();
    if (t < 32) {
      float q0 = part[t * 2] + part[64 + t * 2] + part[128 + t * 2] + part[192 + t * 2] + ob3[0];
      float q1 = part[t * 2 + 1] + part[64 + t * 2 + 1] + part[128 + t * 2 + 1] + part[192 + t * 2 + 1] + ob3[1];
      float m2 = fmaxf(q0, q1);
      float e0 = __expf(q0 - m2), e1 = __expf(q1 - m2);
      float iv = 1.0f / (e0 + e1);
      float2 r; r.x = e0 * iv; r.y = e1 * iv;
      *(float2*)(out + (size_t)(u0 + t) * 2) = r;
    }
  } else {
    // sigmoid -> sel tile in LDS (reuse As; all phase-1 reads are done)
    __syncthreads();
    short* sel = As;
    #pragma unroll
    for (int cb = 0; cb < 4; ++cb) {
      int n = wid * 64 + cb * 16 + lo;
      float bs = b2[n];
      #pragma unroll
      for (int rb = 0; rb < 2; ++rb)
        #pragma unroll
        for (int j = 0; j < 4; ++j) {
          int row = rb * 16 + hi * 4 + j;
          float sig = 1.0f / (1.0f + __expf(-(acc[rb][cb][j] + bs)));
          sel[row * 256 + ((n >> 3) ^ (row & 7)) * 8 + (n & 7)] = (short)pack2(sig, 0.f);
        }
    }
    __syncthreads();
    if (wid < 2) {
      f32x4 acc2[4] = {};
      #pragma unroll
      for (int ks = 0; ks < 8; ++ks) {
        int row = wid * 16 + lo;
        int ca = ks * 4 + hi;
        short8 af = *(const short8*)&sel[row * 256 + (ca ^ (row & 7)) * 8];
        #pragma unroll
        for (int cb = 0; cb < 4; ++cb) {
          short8 bf = *(const short8*)(W3T_s + (size_t)(cb * 16 + lo) * HD + ks * 32 + hi * 8);
          acc2[cb] = __builtin_amdgcn_mfma_f32_16x16x32_bf16(af, bf, acc2[cb], 0, 0, 0);
        }
      }
      float sb3n[4];
      #pragma unroll
      for (int cb = 0; cb < 4; ++cb) sb3n[cb] = sb3[cb * 16 + lo];
      const int ubase = u0 + wid * 16 + hi * 4;
      #pragma unroll
      for (int j = 0; j < 4; ++j) {
        unsigned long long m = connS[ubase + j];
        float v[4]; bool ok[4];
        float mx = -INFINITY;
        #pragma unroll
        for (int cb = 0; cb < 4; ++cb) {
          int n = cb * 16 + lo;
          ok[cb] = (m >> n) & 1ull;
          v[cb] = ok[cb] ? (acc2[cb][j] + sb3n[cb]) : -INFINITY;
          mx = fmaxf(mx, v[cb]);
        }
        #pragma unroll
        for (int off = 1; off < 16; off <<= 1) mx = fmaxf(mx, __shfl_xor(mx, off, 64));
        float e[4], ssum = 0.f;
        #pragma unroll
        for (int cb = 0; cb < 4; ++cb) {
          e[cb] = ok[cb] ? __expf(v[cb] - mx) : 0.f;
          ssum += e[cb];
        }
        #pragma unroll
        for (int off = 1; off < 16; off <<= 1) ssum += __shfl_xor(ssum, off, 64);
        float iv = 1.0f / ssum;
        #pragma unroll
        for (int cb = 0; cb < 4; ++cb) {
          int n = cb * 16 + lo;
          out[(size_t)NUSER * 2 + (size_t)(ubase + j) * SSLOT + n] = e[cb] * iv;
        }
      }
    }
  }
}

// ---------------------------------------------------------------------------
extern "C" void kernel_launch(void* const* d_in, const int* in_sizes, int n_in,
                              void* d_out, int out_size, void* d_ws, size_t ws_size,
                              hipStream_t stream) {
  const float* x_user   = (const float*)d_in[0];
  const float* x_server = (const float*)d_in[1];
  const int*   dst_u2s  = (const int*)d_in[3];
  const int*   dst_u2u  = (const int*)d_in[5];
  const float* oW1 = (const float*)d_in[6];
  const float* ob1 = (const float*)d_in[7];
  const float* oW2 = (const float*)d_in[8];
  const float* ob2 = (const float*)d_in[9];
  const float* oW3 = (const float*)d_in[10];
  const float* ob3 = (const float*)d_in[11];
  const float* sW1 = (const float*)d_in[12];
  const float* sb1 = (const float*)d_in[13];
  const float* sW2 = (const float*)d_in[14];
  const float* sb2 = (const float*)d_in[15];
  const float* sW3 = (const float*)d_in[16];
  const float* sb3 = (const float*)d_in[17];

  char* ws = (char*)d_ws;
  unsigned long long* connS = (unsigned long long*)(ws + 0);         // 128 KB
  unsigned long long* connU = (unsigned long long*)(ws + 131072);    // 512 KB
  __hip_bfloat16* P_o  = (__hip_bfloat16*)(ws + 655360);             // 2 MB
  __hip_bfloat16* P_s  = (__hip_bfloat16*)(ws + 2752512);            // 2 MB
  __hip_bfloat16* Q_o  = (__hip_bfloat16*)(ws + 4849664);            // 8 MB
  __hip_bfloat16* Q_s  = (__hip_bfloat16*)(ws + 13238272);           // 8 MB
  __hip_bfloat16* h1o  = (__hip_bfloat16*)(ws + 21626880);           // 8 MB
  __hip_bfloat16* h1s  = (__hip_bfloat16*)(ws + 30015488);           // 8 MB
  __hip_bfloat16* W2T_o = (__hip_bfloat16*)(ws + 38404096);          // 128 KB
  __hip_bfloat16* W2T_s = (__hip_bfloat16*)(ws + 38535168);          // 128 KB
  __hip_bfloat16* W3T_s = (__hip_bfloat16*)(ws + 38666240);          // 32 KB
  float* out = (float*)d_out;

  k_setup<<<256, 256, 0, stream>>>(dst_u2s, dst_u2u, oW2, sW2, sW3,
                                   connS, connU, W2T_o, W2T_s, W3T_s);
  k_pq<<<SSLOT + UU, 256, 0, stream>>>(x_user, x_server, oW1, sW1, P_o, P_s, Q_o, Q_s);
  k_h1<<<NUSER / 4, 256, 0, stream>>>(connS, connU, P_o, P_s, Q_o, Q_s, ob1, sb1, h1o, h1s);
  k_heads<<<dim3(512, 2), 256, 0, stream>>>(h1o, h1s, W2T_o, W2T_s, ob2, sb2,
                                            oW3, ob3, W3T_s, sb3, connS, out);
}

// Round 6
// 82.449 us; speedup vs baseline: 1.4297x; 1.0076x over previous
//
#include <hip/hip_runtime.h>
#include <hip/hip_bf16.h>
#include <math.h>
#include <cstdint>

#define NUSER 16384   // B*U
#define BB    64
#define UU    256
#define SSLOT 64
#define HD    256
#define KTOT  320     // 64 server slots + 256 user slots
#define DEGS  8
#define DEGU  16

typedef __attribute__((ext_vector_type(8))) short short8;
typedef __attribute__((ext_vector_type(4))) float f32x4;

static __device__ __forceinline__ __hip_bfloat16 f2b(float x) { return __float2bfloat16(x); }
static __device__ __forceinline__ unsigned pack2(float x, float y) {
  union { __hip_bfloat16 h[2]; unsigned u; } cv;
  cv.h[0] = f2b(x); cv.h[1] = f2b(y);
  return cv.u;
}

// ---------------------------------------------------------------------------
// K0a: zero MSU + transpose weights to bf16.
// ---------------------------------------------------------------------------
__global__ __launch_bounds__(256) void k_zero(
    const float* __restrict__ oW2, const float* __restrict__ sW2,
    const float* __restrict__ sW3,
    uint4* __restrict__ msu4,
    __hip_bfloat16* __restrict__ W2T_o, __hip_bfloat16* __restrict__ W2T_s,
    __hip_bfloat16* __restrict__ W3T_s) {
  const int b = blockIdx.x, t = threadIdx.x;
  W2T_o[b * HD + t] = f2b(oW2[t * HD + b]);
  W2T_s[b * HD + t] = f2b(sW2[t * HD + b]);
  if (b < SSLOT) W3T_s[b * HD + t] = f2b(sW3[t * SSLOT + b]);
  uint4 z = {0, 0, 0, 0};
  #pragma unroll
  for (int i = 0; i < 10; ++i)           // 655360 uint4 total
    msu4[i * 65536 + b * 256 + t] = z;
}

// ---------------------------------------------------------------------------
// K0b: connS bitmasks + scatter 1.0bf16 into MSU[u][320].
// ---------------------------------------------------------------------------
__global__ __launch_bounds__(256) void k_scatter(
    const int* __restrict__ dst_u2s, const int* __restrict__ dst_u2u,
    unsigned long long* __restrict__ connS, unsigned short* __restrict__ MSU) {
  const int u = blockIdx.x * 256 + threadIdx.x;
  unsigned long long ms = 0ull;
  #pragma unroll
  for (int i = 0; i < DEGS; ++i) {
    int slot = dst_u2s[u * DEGS + i] & 63;
    ms |= 1ull << slot;
    MSU[u * KTOT + slot] = 0x3F80;       // bf16 1.0
  }
  connS[u] = ms;
  #pragma unroll
  for (int i = 0; i < DEGU; ++i) {
    int slot = dst_u2u[u * DEGU + i] & 255;
    MSU[u * KTOT + 64 + slot] = 0x3F80;
  }
}

// ---------------------------------------------------------------------------
// K1: per-slot partial layer-1 products, stored bf16 (slot-major).
// ---------------------------------------------------------------------------
__global__ __launch_bounds__(256) void k_pq(
    const float* __restrict__ xu, const float* __restrict__ xs,
    const float* __restrict__ oW1, const float* __restrict__ sW1,
    __hip_bfloat16* __restrict__ P_o, __hip_bfloat16* __restrict__ P_s,
    __hip_bfloat16* __restrict__ Q_o, __hip_bfloat16* __restrict__ Q_s) {
  const int t = threadIdx.x;
  const int wg = blockIdx.x;            // 0..63 server slots, 64..319 user slots
  __shared__ float lx[BB * 16];
  const bool isS = wg < SSLOT;
  const int slot = isS ? wg : wg - SSLOT;
  for (int i = t; i < BB * 16; i += 256) {
    int b = i >> 4, d = i & 15;
    lx[i] = isS ? xs[(b * SSLOT + slot) * 16 + d] : xu[(b * UU + slot) * 16 + d];
  }
  __syncthreads();
  float wo[16], wsv[16];
  const int rbase = isS ? slot * 16 : SSLOT * 16 + slot * 16;
  #pragma unroll
  for (int d = 0; d < 16; ++d) {
    wo[d] = oW1[(rbase + d) * HD + t];
    wsv[d] = sW1[(rbase + d) * HD + t];
  }
  __hip_bfloat16* Ro = isS ? P_o : Q_o;
  __hip_bfloat16* Rs = isS ? P_s : Q_s;
  const int rows = isS ? SSLOT : UU;
  for (int b = 0; b < BB; ++b) {
    float ao = 0.f, as = 0.f;
    #pragma unroll
    for (int q = 0; q < 4; ++q) {
      float4 x4 = *(const float4*)&lx[b * 16 + q * 4];
      ao = fmaf(x4.x, wo[q*4+0], ao); as = fmaf(x4.x, wsv[q*4+0], as);
      ao = fmaf(x4.y, wo[q*4+1], ao); as = fmaf(x4.y, wsv[q*4+1], as);
      ao = fmaf(x4.z, wo[q*4+2], ao); as = fmaf(x4.z, wsv[q*4+2], as);
      ao = fmaf(x4.w, wo[q*4+3], ao); as = fmaf(x4.w, wsv[q*4+3], as);
    }
    Ro[(b * rows + slot) * HD + t] = f2b(ao);
    Rs[(b * rows + slot) * HD + t] = f2b(as);
  }
}

// ---------------------------------------------------------------------------
// K2: transpose P,Q -> PQT[b][n][320] (n-major, k-contiguous) via LDS.
// grid (64 b, 2 mlp, 4 n-chunks), 256 thr. 5 k-tiles of 64.
// ---------------------------------------------------------------------------
__global__ __launch_bounds__(256) void k_tr(
    const __hip_bfloat16* __restrict__ P_o, const __hip_bfloat16* __restrict__ P_s,
    const __hip_bfloat16* __restrict__ Q_o, const __hip_bfloat16* __restrict__ Q_s,
    __hip_bfloat16* __restrict__ PQT_o, __hip_bfloat16* __restrict__ PQT_s) {
  const int b = blockIdx.x, mlp = blockIdx.y, nc = blockIdx.z;
  const int n0 = nc * 64;
  const int t = threadIdx.x;
  const __hip_bfloat16* P = mlp ? P_s : P_o;
  const __hip_bfloat16* Q = mlp ? Q_s : Q_o;
  __hip_bfloat16* PQT = mlp ? PQT_s : PQT_o;
  __shared__ __align__(16) short lds[64 * 72];
  for (int kt = 0; kt < 5; ++kt) {
    const __hip_bfloat16* src = (kt == 0) ? (P + (size_t)(b * SSLOT) * HD)
                                          : (Q + (size_t)(b * UU + (kt - 1) * 64) * HD);
    const int kout = (kt == 0) ? 0 : 64 + (kt - 1) * 64;
    #pragma unroll
    for (int i = 0; i < 2; ++i) {
      int c = t + i * 256;
      int row = c >> 3, cc = c & 7;
      *(short8*)&lds[row * 72 + cc * 8] =
          *(const short8*)(src + (size_t)row * HD + n0 + cc * 8);
    }
    __syncthreads();
    #pragma unroll
    for (int i = 0; i < 2; ++i) {
      int c = t + i * 256;
      int nrow = c >> 3, kc = c & 7;
      short8 v;
      #pragma unroll
      for (int e = 0; e < 8; ++e) v[e] = lds[(kc * 8 + e) * 72 + nrow];
      *(short8*)(PQT + (size_t)(b * 256 + n0 + nrow) * KTOT + kout + kc * 8) = v;
    }
    __syncthreads();
  }
}

// ---------------------------------------------------------------------------
// K3: fused mask-GEMM (h1) -> layer-2 GEMM -> heads.
// grid (256 u-tiles of 64, 2 mlps); 4 waves; wave = 64u x 64n quarter.
// ---------------------------------------------------------------------------
__global__ __launch_bounds__(256) void k_fused(
    const unsigned short* __restrict__ MSU,
    const __hip_bfloat16* __restrict__ PQT_o, const __hip_bfloat16* __restrict__ PQT_s,
    const float* __restrict__ ob1, const float* __restrict__ sb1,
    const __hip_bfloat16* __restrict__ W2T_o, const __hip_bfloat16* __restrict__ W2T_s,
    const float* __restrict__ ob2, const float* __restrict__ sb2,
    const float* __restrict__ oW3, const float* __restrict__ ob3,
    const __hip_bfloat16* __restrict__ W3T_s, const float* __restrict__ sb3,
    const unsigned long long* __restrict__ connS,
    float* __restrict__ out) {
  const int mlp = blockIdx.y;
  const int x = blockIdx.x;
  const int blk = (x & 7) * 32 + (x >> 3);      // XCD-affine, bijective (256%8==0)
  const int u0 = blk * 64;
  const int b = u0 >> 8;
  const int t = threadIdx.x, lane = t & 63, wid = t >> 6;
  const int lo = lane & 15, hi = lane >> 4;

  const __hip_bfloat16* PQT = mlp ? PQT_s : PQT_o;
  const __hip_bfloat16* W2T = mlp ? W2T_s : W2T_o;
  const float* b1 = mlp ? sb1 : ob1;
  const float* b2 = mlp ? sb2 : ob2;

  __shared__ __align__(16) char lds[75776];
  short* mk = (short*)lds;               // [64 u][320 k] swizzled   (40960 B)
  short* h1 = (short*)(lds + 40960);     // [64 u][256 n] swizzled   (32768 B), reused as sel
  float* part = (float*)(lds + 73728);   // [4][64][2]               (2048 B)

  // ---- stage mask tile (64 rows x 40 chunks) ----
  {
    const int row = t >> 2;
    #pragma unroll
    for (int i = 0; i < 10; ++i) {
      int cc = (t & 3) + 4 * i;
      *(short8*)&mk[row * KTOT + (cc ^ (row & 7)) * 8] =
          *(const short8*)(MSU + (size_t)(u0 + row) * KTOT + cc * 8);
    }
  }
  __syncthreads();

  // ---- phase 1: h1 = relu(b1 + mask @ PQT^T) ----
  f32x4 acc[4][4] = {};
  #pragma unroll
  for (int kt = 0; kt < 10; ++kt) {
    short8 af[4], bf[4];
    #pragma unroll
    for (int rb = 0; rb < 4; ++rb) {
      int row = rb * 16 + lo;
      int ca = kt * 4 + hi;
      af[rb] = *(const short8*)&mk[row * KTOT + (ca ^ (row & 7)) * 8];
    }
    #pragma unroll
    for (int cb = 0; cb < 4; ++cb) {
      int n = wid * 64 + cb * 16 + lo;
      bf[cb] = *(const short8*)(PQT + (size_t)(b * 256 + n) * KTOT + kt * 32 + hi * 8);
    }
    #pragma unroll
    for (int rb = 0; rb < 4; ++rb)
      #pragma unroll
      for (int cb = 0; cb < 4; ++cb)
        acc[rb][cb] = __builtin_amdgcn_mfma_f32_16x16x32_bf16(af[rb], bf[cb], acc[rb][cb], 0, 0, 0);
  }
  // epilogue-1: bias + relu -> h1 LDS (bf16, swizzled)
  #pragma unroll
  for (int cb = 0; cb < 4; ++cb) {
    int n = wid * 64 + cb * 16 + lo;
    float bv = b1[n];
    #pragma unroll
    for (int rb = 0; rb < 4; ++rb)
      #pragma unroll
      for (int j = 0; j < 4; ++j) {
        int row = rb * 16 + hi * 4 + j;
        float v = fmaxf(acc[rb][cb][j] + bv, 0.f);
        h1[row * 256 + ((n >> 3) ^ (row & 7)) * 8 + (n & 7)] = (short)pack2(v, 0.f);
      }
  }
  __syncthreads();

  // ---- phase 2: h2pre = h1 @ W2 ----
  f32x4 acc2[4][4] = {};
  #pragma unroll
  for (int ks = 0; ks < 8; ++ks) {
    short8 af[4], bf[4];
    #pragma unroll
    for (int rb = 0; rb < 4; ++rb) {
      int row = rb * 16 + lo;
      int ca = ks * 4 + hi;
      af[rb] = *(const short8*)&h1[row * 256 + (ca ^ (row & 7)) * 8];
    }
    #pragma unroll
    for (int cb = 0; cb < 4; ++cb) {
      int n = wid * 64 + cb * 16 + lo;
      bf[cb] = *(const short8*)(W2T + (size_t)n * HD + ks * 32 + hi * 8);
    }
    #pragma unroll
    for (int rb = 0; rb < 4; ++rb)
      #pragma unroll
      for (int cb = 0; cb < 4; ++cb)
        acc2[rb][cb] = __builtin_amdgcn_mfma_f32_16x16x32_bf16(af[rb], bf[cb], acc2[rb][cb], 0, 0, 0);
  }

  // ---- heads ----
  if (mlp == 0) {
    float p0[4][4] = {}, p1[4][4] = {};
    #pragma unroll
    for (int cb = 0; cb < 4; ++cb) {
      int n = wid * 64 + cb * 16 + lo;
      float bs = b2[n], w0 = oW3[2 * n], w1 = oW3[2 * n + 1];
      #pragma unroll
      for (int rb = 0; rb < 4; ++rb)
        #pragma unroll
        for (int j = 0; j < 4; ++j) {
          float sig = 1.0f / (1.0f + __expf(-(acc2[rb][cb][j] + bs)));
          p0[rb][j] = fmaf(sig, w0, p0[rb][j]);
          p1[rb][j] = fmaf(sig, w1, p1[rb][j]);
        }
    }
    #pragma unroll
    for (int rb = 0; rb < 4; ++rb)
      #pragma unroll
      for (int j = 0; j < 4; ++j) {
        #pragma unroll
        for (int off = 1; off < 16; off <<= 1) {
          p0[rb][j] += __shfl_xor(p0[rb][j], off, 64);
          p1[rb][j] += __shfl_xor(p1[rb][j], off, 64);
        }
        if (lo == 0) {
          int row = rb * 16 + hi * 4 + j;
          part[wid * 128 + row * 2 + 0] = p0[rb][j];
          part[wid * 128 + row * 2 + 1] = p1[rb][j];
        }
      }
    __syncthreads();
    if (t < 64) {
      float q0 = part[t * 2] + part[128 + t * 2] + part[256 + t * 2] + part[384 + t * 2] + ob3[0];
      float q1 = part[t * 2 + 1] + part[128 + t * 2 + 1] + part[256 + t * 2 + 1] + part[384 + t * 2 + 1] + ob3[1];
      float m2 = fmaxf(q0, q1);
      float e0 = __expf(q0 - m2), e1 = __expf(q1 - m2);
      float iv = 1.0f / (e0 + e1);
      float2 r; r.x = e0 * iv; r.y = e1 * iv;
      *(float2*)(out + (size_t)(u0 + t) * 2) = r;
    }
  } else {
    __syncthreads();                      // all phase-2 h1 reads complete
    short* sel = h1;
    #pragma unroll
    for (int cb = 0; cb < 4; ++cb) {
      int n = wid * 64 + cb * 16 + lo;
      float bs = b2[n];
      #pragma unroll
      for (int rb = 0; rb < 4; ++rb)
        #pragma unroll
        for (int j = 0; j < 4; ++j) {
          int row = rb * 16 + hi * 4 + j;
          float sig = 1.0f / (1.0f + __expf(-(acc2[rb][cb][j] + bs)));
          sel[row * 256 + ((n >> 3) ^ (row & 7)) * 8 + (n & 7)] = (short)pack2(sig, 0.f);
        }
    }
    __syncthreads();
    // sel GEMM: wave wid -> users wid*16..+16, all 64 slots
    f32x4 acc3[4] = {};
    #pragma unroll
    for (int ks = 0; ks < 8; ++ks) {
      int row = wid * 16 + lo;
      int ca = ks * 4 + hi;
      short8 af = *(const short8*)&sel[row * 256 + (ca ^ (row & 7)) * 8];
      #pragma unroll
      for (int cb = 0; cb < 4; ++cb) {
        short8 bf = *(const short8*)(W3T_s + (size_t)(cb * 16 + lo) * HD + ks * 32 + hi * 8);
        acc3[cb] = __builtin_amdgcn_mfma_f32_16x16x32_bf16(af, bf, acc3[cb], 0, 0, 0);
      }
    }
    float sb3n[4];
    #pragma unroll
    for (int cb = 0; cb < 4; ++cb) sb3n[cb] = sb3[cb * 16 + lo];
    const int ubase = u0 + wid * 16 + hi * 4;
    #pragma unroll
    for (int j = 0; j < 4; ++j) {
      unsigned long long m = connS[ubase + j];
      float v[4]; bool ok[4];
      float mx = -INFINITY;
      #pragma unroll
      for (int cb = 0; cb < 4; ++cb) {
        int n = cb * 16 + lo;
        ok[cb] = (m >> n) & 1ull;
        v[cb] = ok[cb] ? (acc3[cb][j] + sb3n[cb]) : -INFINITY;
        mx = fmaxf(mx, v[cb]);
      }
      #pragma unroll
      for (int off = 1; off < 16; off <<= 1) mx = fmaxf(mx, __shfl_xor(mx, off, 64));
      float e[4], ssum = 0.f;
      #pragma unroll
      for (int cb = 0; cb < 4; ++cb) {
        e[cb] = ok[cb] ? __expf(v[cb] - mx) : 0.f;
        ssum += e[cb];
      }
      #pragma unroll
      for (int off = 1; off < 16; off <<= 1) ssum += __shfl_xor(ssum, off, 64);
      float iv = 1.0f / ssum;
      #pragma unroll
      for (int cb = 0; cb < 4; ++cb) {
        int n = cb * 16 + lo;
        out[(size_t)NUSER * 2 + (size_t)(ubase + j) * SSLOT + n] = e[cb] * iv;
      }
    }
  }
}

// ---------------------------------------------------------------------------
extern "C" void kernel_launch(void* const* d_in, const int* in_sizes, int n_in,
                              void* d_out, int out_size, void* d_ws, size_t ws_size,
                              hipStream_t stream) {
  const float* x_user   = (const float*)d_in[0];
  const float* x_server = (const float*)d_in[1];
  const int*   dst_u2s  = (const int*)d_in[3];
  const int*   dst_u2u  = (const int*)d_in[5];
  const float* oW1 = (const float*)d_in[6];
  const float* ob1 = (const float*)d_in[7];
  const float* oW2 = (const float*)d_in[8];
  const float* ob2 = (const float*)d_in[9];
  const float* oW3 = (const float*)d_in[10];
  const float* ob3 = (const float*)d_in[11];
  const float* sW1 = (const float*)d_in[12];
  const float* sb1 = (const float*)d_in[13];
  const float* sW2 = (const float*)d_in[14];
  const float* sb2 = (const float*)d_in[15];
  const float* sW3 = (const float*)d_in[16];
  const float* sb3 = (const float*)d_in[17];

  char* ws = (char*)d_ws;
  unsigned long long* connS = (unsigned long long*)(ws + 0);          // 128 KB
  unsigned short* MSU  = (unsigned short*)(ws + 131072);              // 10.0 MB
  __hip_bfloat16* P_o  = (__hip_bfloat16*)(ws + 10616832);            // 2 MB
  __hip_bfloat16* P_s  = (__hip_bfloat16*)(ws + 12713984);            // 2 MB
  __hip_bfloat16* Q_o  = (__hip_bfloat16*)(ws + 14811136);            // 8 MB
  __hip_bfloat16* Q_s  = (__hip_bfloat16*)(ws + 23199744);            // 8 MB
  __hip_bfloat16* PQT_o = (__hip_bfloat16*)(ws + 31588352);           // 10 MB
  __hip_bfloat16* PQT_s = (__hip_bfloat16*)(ws + 42074112);           // 10 MB
  __hip_bfloat16* W2T_o = (__hip_bfloat16*)(ws + 52559872);           // 128 KB
  __hip_bfloat16* W2T_s = (__hip_bfloat16*)(ws + 52690944);           // 128 KB
  __hip_bfloat16* W3T_s = (__hip_bfloat16*)(ws + 52822016);           // 32 KB
  float* out = (float*)d_out;

  k_zero<<<256, 256, 0, stream>>>(oW2, sW2, sW3, (uint4*)MSU, W2T_o, W2T_s, W3T_s);
  k_scatter<<<64, 256, 0, stream>>>(dst_u2s, dst_u2u, connS, MSU);
  k_pq<<<KTOT, 256, 0, stream>>>(x_user, x_server, oW1, sW1, P_o, P_s, Q_o, Q_s);
  k_tr<<<dim3(64, 2, 4), 256, 0, stream>>>(P_o, P_s, Q_o, Q_s, PQT_o, PQT_s);
  k_fused<<<dim3(256, 2), 256, 0, stream>>>(MSU, PQT_o, PQT_s, ob1, sb1,
                                            W2T_o, W2T_s, ob2, sb2,
                                            oW3, ob3, W3T_s, sb3, connS, out);
}